// Round 11
// baseline (4148.237 us; speedup 1.0000x reference)
//
#include <hip/hip_runtime.h>
#include <math.h>

// ---------------------------------------------------------------------------
// LiteEval gated dual-LSTM.  Round 11 = R10 with the LDS-duplication compile
// fix: gcore256 takes the 128KB LDS buffer as a parameter (declared ONCE per
// __global__ wrapper) so the two-callsite router kernel doesn't double it.
//  * fe (EPI0) + Gx_s (EPI1) merged into one 512-thr launch (machine-filling).
//  * input packs merged into one launch per chunk.
//  * Gx_l on proven gmm256 2-phase body + cohort XCD map.
//  * stepg / step_upd / images / f16-split x3-MFMA unchanged.
// ---------------------------------------------------------------------------

typedef _Float16 f16;
typedef _Float16 f16x4 __attribute__((ext_vector_type(4)));
typedef _Float16 f16x8 __attribute__((ext_vector_type(8)));
typedef float f32x4 __attribute__((ext_vector_type(4)));

__device__ __forceinline__ float sigf(float x) { return 1.0f / (1.0f + expf(-x)); }

__device__ __forceinline__ void gload16(const f16* g, f16* l) {
  __builtin_amdgcn_global_load_lds((const __attribute__((address_space(1))) void*)g,
                                   (__attribute__((address_space(3))) void*)l, 16, 0, 0);
}

// bijective 2D cohort XCD mapping (guarded): XCD x owns (gA/2) x (gB/4) tiles
__device__ __forceinline__ void cohort_map(int lin, int gA, int gB, int swz,
                                           int& pA, int& pB) {
  if (swz && (gA & 1) == 0 && (gB & 3) == 0) {
    const int xcd = lin & 7;
    const int j = lin >> 3;
    const int pbp = gB >> 2;
    pB = (xcd & 3) * pbp + (j % pbp);
    pA = (xcd >> 2) * (gA >> 1) + (j / pbp);
  } else {
    pB = lin % gB;
    pA = lin / gB;
  }
}

// ---------------------------------------------------------------------------
// pack f32 [R][C] row-major (optional chunk time-major row remap) -> image
// image elem (row = p*128 + j*16 + (lane&15), k = kt*32 + (lane>>4)*8 + e)
// at f16 offset ((p*KT + kt)*8 + j)*512 + lane*8 + e           (KT = K/32)
__device__ __forceinline__ void pack_body(const float* __restrict__ src,
    int C, int KT, int t0, int map, f16* __restrict__ dh, f16* __restrict__ dl,
    int gid)
{
  int lane = gid & 63;
  int j = (gid >> 6) & 7;
  int pk = gid >> 9;
  int p = pk / KT, kt = pk - p * KT;
  int r = p * 128 + j * 16 + (lane & 15);
  int rg = map ? (((r & 255) << 6) + t0 + (r >> 8)) : r;
  int c = kt * 32 + (lane >> 4) * 8;
  const float* s = src + (long long)rg * C + c;
  float4 v0 = *(const float4*)s, v1 = *(const float4*)(s + 4);
  f16x8 h, l;
  h[0]=(f16)v0.x; l[0]=(f16)(v0.x-(float)h[0]);
  h[1]=(f16)v0.y; l[1]=(f16)(v0.y-(float)h[1]);
  h[2]=(f16)v0.z; l[2]=(f16)(v0.z-(float)h[2]);
  h[3]=(f16)v0.w; l[3]=(f16)(v0.w-(float)h[3]);
  h[4]=(f16)v1.x; l[4]=(f16)(v1.x-(float)h[4]);
  h[5]=(f16)v1.y; l[5]=(f16)(v1.y-(float)h[5]);
  h[6]=(f16)v1.z; l[6]=(f16)(v1.z-(float)h[6]);
  h[7]=(f16)v1.w; l[7]=(f16)(v1.w-(float)h[7]);
  *(f16x8*)(dh + (long long)gid * 8) = h;
  *(f16x8*)(dl + (long long)gid * 8) = l;
}

__global__ __launch_bounds__(256) void pack_img(const float* __restrict__ src,
    int C, int KT, int t0, int map, f16* __restrict__ dh, f16* __restrict__ dl,
    int slots)
{
  int gid = blockIdx.x * 256 + threadIdx.x;
  if (gid >= slots) return;
  pack_body(src, C, KT, t0, map, dh, dl, gid);
}

// merged per-chunk input pack: blocks [0,bx) -> x, [bx,..) -> xs
__global__ __launch_bounds__(256) void pack2_k(int bx,
    const float* __restrict__ x, const float* __restrict__ xs, int t0,
    f16* __restrict__ xh, f16* __restrict__ xl,
    f16* __restrict__ xsh, f16* __restrict__ xsl)
{
  if ((int)blockIdx.x < bx) {
    int gid = blockIdx.x * 256 + threadIdx.x;
    pack_body(x, 2048, 64, t0, 1, xh, xl, gid);
  } else {
    int gid = (blockIdx.x - bx) * 256 + threadIdx.x;
    pack_body(xs, 1280, 40, t0, 1, xsh, xsl, gid);
  }
}

// ---------------------------------------------------------------------------
// 256x256-tile split-f16 MFMA GEMM core on images (R5 structure).
// 512 thr = 8 waves (2M x 4N), BK=32, LDS (passed in) 2 x 64KB dbuf, 2-phase.
// EPI 0: relu((v+e0)*e1*s+e2) -> image out via quarter-tile f32 bounce
// EPI 1: v + e0[col] + e1[col] -> f32 row-major C
template <int EPI>
__device__ __forceinline__ void gcore256(char* smem, int pA, int pB,
    const f16* __restrict__ Ah0, const f16* __restrict__ Al0, int KT0,
    const f16* __restrict__ Ah1, const f16* __restrict__ Al1, int KT1,
    const f16* __restrict__ Bh, const f16* __restrict__ Bl, int KTB,
    float* __restrict__ C, int ldc,
    f16* __restrict__ Ch, f16* __restrict__ Cl, int KTout,
    const float* __restrict__ e0, const float* __restrict__ e1,
    const float* __restrict__ e2)
{
  f16 (*sm)[4][8192] = (f16 (*)[4][8192])smem;   // [buf][Ah,Al,Bh,Bl][...]
  const int tid = threadIdx.x;
  const int w = tid >> 6, lane = tid & 63;
  const int wr = w >> 2, wc = w & 3;             // 2 M-waves x 4 N-waves
  const int fr = lane & 15, fq = lane >> 4;
  const int sarr = w >> 1, shalf = w & 1;        // staging: array, panel half

  const int nt = KT0 + KT1;

  auto stage = [&](int buf, int kt) {
    const f16* base;
    if (sarr >= 2) {
      base = ((sarr == 2) ? Bh : Bl) + ((long long)(pB * 2 + shalf) * KTB + kt) * 4096;
    } else if (kt < KT0) {
      base = ((sarr == 0) ? Ah0 : Al0) + ((long long)(pA * 2 + shalf) * KT0 + kt) * 4096;
    } else {
      base = ((sarr == 0) ? Ah1 : Al1) + ((long long)(pA * 2 + shalf) * KT1 + (kt - KT0)) * 4096;
    }
    f16* dst = &sm[buf][sarr][shalf * 4096];
#pragma unroll
    for (int j = 0; j < 8; ++j)
      gload16(base + j * 512 + lane * 8, dst + j * 512);
  };

  f32x4 acc[8][4];
#pragma unroll
  for (int m = 0; m < 8; ++m)
#pragma unroll
    for (int n = 0; n < 4; ++n) acc[m][n] = (f32x4){0.f, 0.f, 0.f, 0.f};

  stage(0, 0);
  __syncthreads();
  int cur = 0;
  for (int kt = 0; kt < nt; ++kt) {
    if (kt + 1 < nt) stage(cur ^ 1, kt + 1);     // prefetch next K-tile
    f16x8 bh_[4], bl_[4];
#pragma unroll
    for (int n = 0; n < 4; ++n) {
      bh_[n] = *(const f16x8*)&sm[cur][2][(wc * 4 + n) * 512 + lane * 8];
      bl_[n] = *(const f16x8*)&sm[cur][3][(wc * 4 + n) * 512 + lane * 8];
    }
#pragma unroll
    for (int m = 0; m < 8; ++m) {
      f16x8 ah = *(const f16x8*)&sm[cur][0][wr * 4096 + m * 512 + lane * 8];
      f16x8 al = *(const f16x8*)&sm[cur][1][wr * 4096 + m * 512 + lane * 8];
#pragma unroll
      for (int n = 0; n < 4; ++n) {
        acc[m][n] = __builtin_amdgcn_mfma_f32_16x16x32_f16(ah, bh_[n], acc[m][n], 0, 0, 0);
        acc[m][n] = __builtin_amdgcn_mfma_f32_16x16x32_f16(ah, bl_[n], acc[m][n], 0, 0, 0);
        acc[m][n] = __builtin_amdgcn_mfma_f32_16x16x32_f16(al, bh_[n], acc[m][n], 0, 0, 0);
      }
    }
    __syncthreads();                             // drains prefetch; guards dbuf
    cur ^= 1;
  }

  if constexpr (EPI == 1) {
#pragma unroll
    for (int m = 0; m < 8; ++m) {
#pragma unroll
      for (int n = 0; n < 4; ++n) {
        const int col = pB * 256 + wc * 64 + n * 16 + fr;
        const float add = e0[col] + e1[col];
#pragma unroll
        for (int r = 0; r < 4; ++r) {
          const int row = pA * 256 + wr * 128 + m * 16 + fq * 4 + r;
          C[(long long)row * ldc + col] = acc[m][n][r] + add;
        }
      }
    }
  } else {
    // BN+ReLU -> image out via quarter-tile (64-row) f32 LDS bounce
    float* cb = (float*)smem;
    const int CBLD = 260;
    for (int q = 0; q < 4; ++q) {
      __syncthreads();
      if (wr == (q >> 1)) {
#pragma unroll
        for (int mm = 0; mm < 4; ++mm) {
          const int m = (q & 1) * 4 + mm;
#pragma unroll
          for (int n = 0; n < 4; ++n) {
            const int colL = wc * 64 + n * 16 + fr;
            const int colG = pB * 256 + colL;
            const float p0 = e0[colG], p1 = e1[colG] * 0.99999500003750f, p2 = e2[colG];
#pragma unroll
            for (int r = 0; r < 4; ++r) {
              const int rq = mm * 16 + fq * 4 + r;
              cb[rq * CBLD + colL] = fmaxf((acc[m][n][r] + p0) * p1 + p2, 0.f);
            }
          }
        }
      }
      __syncthreads();
      const int ktl = w;
      const int p_out = pA * 2 + (q >> 1);
#pragma unroll
      for (int jp = 0; jp < 4; ++jp) {
        const int rL = jp * 16 + fr;
        const float* s = &cb[rL * CBLD + ktl * 32 + fq * 8];
        float4 v0 = *(const float4*)s, v1 = *(const float4*)(s + 4);
        float vv[8] = {v0.x, v0.y, v0.z, v0.w, v1.x, v1.y, v1.z, v1.w};
        f16x8 h, l;
#pragma unroll
        for (int e = 0; e < 8; ++e) {
          h[e] = (f16)vv[e]; l[e] = (f16)(vv[e] - (float)h[e]);
        }
        const int j_img = (q & 1) * 4 + jp;
        const long long o =
            (((long long)p_out * KTout + (pB * 8 + ktl)) * 8 + j_img) * 512 + lane * 8;
        *(f16x8*)(Ch + o) = h;
        *(f16x8*)(Cl + o) = l;
      }
    }
  }
}

// 1-D grid wrapper (cohort optional)
template <int EPI>
__global__ __launch_bounds__(512, 1) void gmm256w(
    int gA, int gB, int swz,
    const f16* __restrict__ Ah0, const f16* __restrict__ Al0, int KT0,
    const f16* __restrict__ Ah1, const f16* __restrict__ Al1, int KT1,
    const f16* __restrict__ Bh, const f16* __restrict__ Bl, int KTB,
    float* __restrict__ C, int ldc,
    f16* __restrict__ Ch, f16* __restrict__ Cl, int KTout,
    const float* __restrict__ e0, const float* __restrict__ e1,
    const float* __restrict__ e2)
{
  __shared__ __align__(16) char smem[131072];
  int pA, pB;
  cohort_map(blockIdx.x, gA, gB, swz, pA, pB);
  gcore256<EPI>(smem, pA, pB, Ah0, Al0, KT0, Ah1, Al1, KT1, Bh, Bl, KTB,
                C, ldc, Ch, Cl, KTout, e0, e1, e2);
}

// merged fe (EPI0, image out) + Gx_s (EPI1, f32 out) launch: 2*gA*8 blocks
__global__ __launch_bounds__(512, 1) void fegxs_k(int gA,
    const f16* __restrict__ xIh, const f16* __restrict__ xIl,
    const f16* __restrict__ WpIh, const f16* __restrict__ WpIl,
    f16* __restrict__ feIh, f16* __restrict__ feIl,
    const float* __restrict__ b_p, const float* __restrict__ g_p,
    const float* __restrict__ be_p,
    const f16* __restrict__ sfIh, const f16* __restrict__ sfIl,
    const f16* __restrict__ WisIh, const f16* __restrict__ WisIl,
    float* __restrict__ GxsC,
    const float* __restrict__ bih_s, const float* __restrict__ bhh_s)
{
  __shared__ __align__(16) char smem[131072];
  const int half = gA * 8;
  if ((int)blockIdx.x < half) {
    const int lin = blockIdx.x;
    gcore256<0>(smem, lin >> 3, lin & 7,
                xIh, xIl, 64, nullptr, nullptr, 0, WpIh, WpIl, 64,
                nullptr, 0, feIh, feIl, 64, b_p, g_p, be_p);
  } else {
    const int lin = blockIdx.x - half;
    gcore256<1>(smem, lin >> 3, lin & 7,
                sfIh, sfIl, 16, nullptr, nullptr, 0, WisIh, WisIl, 16,
                GxsC, 2048, nullptr, nullptr, 0, bih_s, bhh_s, nullptr);
  }
}

// ---------------------------------------------------------------------------
// 128x128-tile split-MFMA core (2-phase dbuf) — sequential stepg only.
// EPI 2: v + G[idx] -> f32 row-major C
__device__ __forceinline__ void gcore_step(
    int pA, int pB,
    const f16* __restrict__ Ah0, const f16* __restrict__ Al0, int KT0,
    const f16* __restrict__ Bh, const f16* __restrict__ Bl, int KTB,
    float* __restrict__ C, int ldc, const float* __restrict__ G)
{
  constexpr int NU = 8;
  __shared__ __align__(16) f16 smem[2][32 * 512];

  const int tid = threadIdx.x;
  const int w = tid >> 6, lane = tid & 63;
  const int wr = w >> 1, wc = w & 1;
  const int fr = lane & 15, fq = lane >> 4;

  const f16* up[NU];
#pragma unroll
  for (int i = 0; i < NU; ++i) {
    const int u = w * NU + i;
    const f16* src;
    if (u < 16) {
      const int j = u & 7;
      src = ((u < 8) ? Ah0 : Al0) + (((long long)pA * KT0) * 8 + j) * 512;
    } else {
      const int j = u - 16;
      const f16* IMG = (j < 8) ? Bh : Bl;
      src = IMG + (((long long)pB * KTB) * 8 + (j & 7)) * 512;
    }
    up[i] = src + lane * 8;
  }
  auto stage = [&](int buf) {
#pragma unroll
    for (int i = 0; i < NU; ++i) {
      gload16(up[i], &smem[buf][(w * NU + i) * 512]);
      up[i] += 4096;
    }
  };

  f32x4 acc[4][4];
#pragma unroll
  for (int m = 0; m < 4; ++m)
#pragma unroll
    for (int n = 0; n < 4; ++n) acc[m][n] = (f32x4){0.f, 0.f, 0.f, 0.f};

  stage(0);
  __syncthreads();
  int cur = 0;
  for (int kt = 0; kt < KT0; ++kt) {
    if (kt + 1 < KT0) stage(cur ^ 1);
    const f16* sb = smem[cur];
    f16x8 bh_[4], bl_[4];
#pragma unroll
    for (int n = 0; n < 4; ++n) {
      const int jb = wc * 4 + n;
      bh_[n] = *(const f16x8*)&sb[(16 + jb) * 512 + lane * 8];
      bl_[n] = *(const f16x8*)&sb[(24 + jb) * 512 + lane * 8];
    }
#pragma unroll
    for (int m = 0; m < 4; ++m) {
      const int ja = wr * 4 + m;
      f16x8 ah = *(const f16x8*)&sb[ja * 512 + lane * 8];
      f16x8 al = *(const f16x8*)&sb[(8 + ja) * 512 + lane * 8];
#pragma unroll
      for (int n = 0; n < 4; ++n) {
        acc[m][n] = __builtin_amdgcn_mfma_f32_16x16x32_f16(ah, bh_[n], acc[m][n], 0, 0, 0);
        acc[m][n] = __builtin_amdgcn_mfma_f32_16x16x32_f16(ah, bl_[n], acc[m][n], 0, 0, 0);
        acc[m][n] = __builtin_amdgcn_mfma_f32_16x16x32_f16(al, bh_[n], acc[m][n], 0, 0, 0);
      }
    }
    __syncthreads();
    cur ^= 1;
  }

#pragma unroll
  for (int m = 0; m < 4; ++m) {
#pragma unroll
    for (int n = 0; n < 4; ++n) {
      const int col = pB * 128 + wc * 64 + n * 16 + fr;
#pragma unroll
      for (int r = 0; r < 4; ++r) {
        const int row = pA * 128 + wr * 64 + m * 16 + fq * 4 + r;
        const long long idx = (long long)row * ldc + col;
        C[idx] = acc[m][n][r] + G[idx];
      }
    }
  }
}

// per-step recurrent GEMM, 96 blocks, fixed XCD mapping (weights L2-resident)
__global__ __launch_bounds__(256) void stepg_k(
    const f16* __restrict__ hlh, const f16* __restrict__ hll,
    const f16* __restrict__ hsh, const f16* __restrict__ hsl,
    const f16* __restrict__ Whlh, const f16* __restrict__ Whll,
    const f16* __restrict__ Whsh, const f16* __restrict__ Whsl,
    const float* __restrict__ Gl, const float* __restrict__ Gs,
    float* __restrict__ gl, float* __restrict__ gs)
{
  const int lin = blockIdx.x;          // 96 blocks
  const int xc = lin & 7, j = lin >> 3;
  if (j < 8) {
    gcore_step(j >> 2, xc * 4 + (j & 3), hlh, hll, 32, Whlh, Whll, 32,
               gl, 4096, Gl);
  } else {
    const int jj = j - 8;
    gcore_step(jj >> 1, xc * 2 + (jj & 1), hsh, hsl, 16, Whsh, Whsl, 16,
               gs, 2048, Gs);
  }
}

// zs from sf image (chunk): zs[bt,g] = sfeats[bt,:512] . W_g[g,:512]
__global__ __launch_bounds__(256) void zs_img_k(const f16* __restrict__ sfh,
    const f16* __restrict__ sfl, const float* __restrict__ Wg,
    float* __restrict__ zs, int t0)
{
  const int wv = threadIdx.x >> 6, lane = threadIdx.x & 63;
  const int rr = blockIdx.x * 4 + wv;
  const int p = rr >> 7, j = (rr >> 4) & 7, fr = rr & 15;
  const int kt = lane >> 2, fq = lane & 3;
  const long long a = (((long long)p * 16 + kt) * 8 + j) * 512 + (fq * 16 + fr) * 8;
  f16x8 h8 = *(const f16x8*)(sfh + a);
  f16x8 l8 = *(const f16x8*)(sfl + a);
  const int k0 = kt * 32 + fq * 8;
  float z0 = 0.f, z1 = 0.f;
#pragma unroll
  for (int i = 0; i < 8; ++i) {
    float s = (float)h8[i] + (float)l8[i];
    z0 += s * Wg[k0 + i]; z1 += s * Wg[2560 + k0 + i];
  }
#pragma unroll
  for (int off = 32; off > 0; off >>= 1) {
    z0 += __shfl_down(z0, off);
    z1 += __shfl_down(z1, off);
  }
  if (lane == 0) {
    const int bt = ((rr & 255) << 6) + t0 + (rr >> 8);
    zs[bt * 2] = z0; zs[bt * 2 + 1] = z1;
  }
}

// fused per-step update: gate argmax + small-cell + large-cell blend + write
// the NEW h-state images.
__global__ __launch_bounds__(256) void step_upd(
    const float* __restrict__ gl, const float* __restrict__ gs,
    const float* __restrict__ hl_o, const float* __restrict__ cl_o,
    const float* __restrict__ cs_o,
    float* __restrict__ hl_n, float* __restrict__ cl_n,
    float* __restrict__ hs_n, float* __restrict__ cs_n,
    f16* __restrict__ hlIh, f16* __restrict__ hlIl,
    f16* __restrict__ hsIh, f16* __restrict__ hsIl,
    const float* __restrict__ zs, const float* __restrict__ Wg,
    const float* __restrict__ bg, float* __restrict__ rout, int t)
{
  const int b = blockIdx.x, tid = threadIdx.x;
  __shared__ float red0[256], red1[256];
  __shared__ float shs[512], scs[512];
  __shared__ float rsh[2];

  const int pb = b >> 7, jb = (b >> 4) & 7, frb = b & 15;

  float4 h4 = *(const float4*)(hl_o + (long long)b * 1024 + tid * 4);
  float4 c4 = *(const float4*)(cl_o + (long long)b * 1024 + tid * 4);
  float4 w0h = *(const float4*)(Wg + 512 + tid * 4);
  float4 w0c = *(const float4*)(Wg + 1536 + tid * 4);
  float4 w1h = *(const float4*)(Wg + 2560 + 512 + tid * 4);
  float4 w1c = *(const float4*)(Wg + 2560 + 1536 + tid * 4);
  red0[tid] = h4.x * w0h.x + h4.y * w0h.y + h4.z * w0h.z + h4.w * w0h.w
            + c4.x * w0c.x + c4.y * w0c.y + c4.z * w0c.z + c4.w * w0c.w;
  red1[tid] = h4.x * w1h.x + h4.y * w1h.y + h4.z * w1h.z + h4.w * w1h.w
            + c4.x * w1c.x + c4.y * w1c.y + c4.z * w1c.z + c4.w * w1c.w;

  {
    const float* gb = gs + (long long)b * 2048;
#pragma unroll
    for (int e = 0; e < 2; ++e) {
      const int n = tid * 2 + e;
      float gi = gb[n], gf = gb[512 + n], gg = gb[1024 + n], go = gb[1536 + n];
      float c2 = sigf(gf) * cs_o[b * 512 + n] + sigf(gi) * tanhf(gg);
      float h2 = sigf(go) * tanhf(c2);
      shs[n] = h2; scs[n] = c2;
      hs_n[b * 512 + n] = h2; cs_n[b * 512 + n] = c2;
      const int kt = n >> 5, fqn = (n >> 3) & 3, en = n & 7;
      const long long o = (((long long)pb * 16 + kt) * 8 + jb) * 512
                        + (fqn * 16 + frb) * 8 + en;
      f16 hh = (f16)h2;
      hsIh[o] = hh; hsIl[o] = (f16)(h2 - (float)hh);
    }
  }
  __syncthreads();
  for (int s = 128; s > 0; s >>= 1) {
    if (tid < s) { red0[tid] += red0[tid + s]; red1[tid] += red1[tid + s]; }
    __syncthreads();
  }
  if (tid == 0) {
    float z0 = red0[0] + zs[(b * 64 + t) * 2 + 0] + bg[0];
    float z1 = red1[0] + zs[(b * 64 + t) * 2 + 1] + bg[1];
    int hard = (z1 > z0) ? 1 : 0;   // jnp.argmax ties -> 0
    rsh[0] = hard ? 0.0f : 1.0f; rsh[1] = hard ? 1.0f : 0.0f;
    rout[b * 2 + 0] = rsh[0]; rout[b * 2 + 1] = rsh[1];
  }
  __syncthreads();
  const float r0 = rsh[0], r1 = rsh[1];

  {
    const float* glb = gl + (long long)b * 4096;
    const int n = tid * 4;
    float4 gi4 = *(const float4*)(glb + n);
    float4 gf4 = *(const float4*)(glb + 1024 + n);
    float4 gg4 = *(const float4*)(glb + 2048 + n);
    float4 go4 = *(const float4*)(glb + 3072 + n);
    float4 co4 = *(const float4*)(cl_o + (long long)b * 1024 + n);
    float4 ho4 = *(const float4*)(hl_o + (long long)b * 1024 + n);
    float gi[4] = {gi4.x, gi4.y, gi4.z, gi4.w};
    float gf[4] = {gf4.x, gf4.y, gf4.z, gf4.w};
    float gg[4] = {gg4.x, gg4.y, gg4.z, gg4.w};
    float go[4] = {go4.x, go4.y, go4.z, go4.w};
    float co[4] = {co4.x, co4.y, co4.z, co4.w};
    float ho[4] = {ho4.x, ho4.y, ho4.z, ho4.w};
    float hv[4], cv[4];
    f16x4 ih, il;
#pragma unroll
    for (int e = 0; e < 4; ++e) {
      float cln = sigf(gf[e]) * co[e] + sigf(gi[e]) * tanhf(gg[e]);
      float hln = sigf(go[e]) * tanhf(cln);
      float ph = (n + e < 512) ? shs[n + e] : ho[e];
      float pc = (n + e < 512) ? scs[n + e] : co[e];
      hv[e] = r0 * hln + r1 * ph;
      cv[e] = r0 * cln + r1 * pc;
      ih[e] = (f16)hv[e]; il[e] = (f16)(hv[e] - (float)ih[e]);
    }
    float4 hw = {hv[0], hv[1], hv[2], hv[3]};
    float4 cw = {cv[0], cv[1], cv[2], cv[3]};
    *(float4*)(hl_n + (long long)b * 1024 + n) = hw;
    *(float4*)(cl_n + (long long)b * 1024 + n) = cw;
    const int kt = n >> 5, fqn = (n >> 3) & 3, en = n & 7;
    const long long o = (((long long)pb * 32 + kt) * 8 + jb) * 512
                      + (fqn * 16 + frb) * 8 + en;
    *(f16x4*)(hlIh + o) = ih;
    *(f16x4*)(hlIl + o) = il;
  }
}

// logits = h_l @ W_c^T + b_c
__global__ __launch_bounds__(256) void logits_k(const float* __restrict__ hl,
                                                const float* __restrict__ Wc,
                                                const float* __restrict__ bc,
                                                float* __restrict__ out)
{
  __shared__ float hsd[1024];
  const int b = blockIdx.x, tid = threadIdx.x;
  *(float4*)(hsd + tid * 4) = *(const float4*)(hl + (long long)b * 1024 + tid * 4);
  __syncthreads();
  if (tid < 239) {
    const float* w = Wc + (long long)tid * 1024;
    float s = 0.0f;
    for (int k = 0; k < 1024; k += 4) {
      float4 wv = *(const float4*)(w + k);
      s += hsd[k] * wv.x + hsd[k + 1] * wv.y + hsd[k + 2] * wv.z + hsd[k + 3] * wv.w;
    }
    out[(long long)b * 239 + tid] = s + bc[tid];
  }
}

// ===========================================================================
// all-f32 fallback (tiny workspace) — Round-1 proven path
#define BKK 32
template <int BM, int BN, int TM, int TN, int EPI>
__global__ __launch_bounds__(256) void gemm_nt(
    int M, int N,
    const float* __restrict__ A0, long long as0, const float* __restrict__ B0, long long bs0, int K0,
    const float* __restrict__ A1, long long as1, const float* __restrict__ B1, long long bs1, int K1,
    const float* __restrict__ A2, long long as2, const float* __restrict__ B2, long long bs2, int K2,
    float* __restrict__ C, long long ldc,
    const float* __restrict__ e0, const float* __restrict__ e1, const float* __restrict__ e2)
{
  __shared__ float As[BKK][BM + 4];
  __shared__ float Bs[BKK][BN + 4];
  const int tid = threadIdx.x;
  const int m0 = blockIdx.x * BM;
  const int n0 = blockIdx.y * BN;
  constexpr int C4 = BKK / 4;
  constexpr int RPP = 256 / C4;
  constexpr int APASS = BM / RPP;
  constexpr int BPASS = BN / RPP;
  const int lr = tid / C4;
  const int lc = tid % C4;
  float4 pa[APASS], pb[BPASS];
  const int nt = (K0 + K1 + K2) / BKK;
  auto load = [&](int kt) {
    const int kg = kt * BKK;
    const float* ap; long long as_; const float* bp; long long bs_;
    if (kg < K0)           { ap = A0 + kg;          as_ = as0; bp = B0 + kg;          bs_ = bs0; }
    else if (kg < K0 + K1) { int kl = kg - K0;      ap = A1 + kl; as_ = as1; bp = B1 + kl; bs_ = bs1; }
    else                   { int kl = kg - K0 - K1; ap = A2 + kl; as_ = as2; bp = B2 + kl; bs_ = bs2; }
#pragma unroll
    for (int p = 0; p < APASS; p++) {
      int r = lr + p * RPP;
      pa[p] = *(const float4*)(ap + (long long)(m0 + r) * as_ + lc * 4);
    }
#pragma unroll
    for (int p = 0; p < BPASS; p++) {
      int r = lr + p * RPP;
      pb[p] = *(const float4*)(bp + (long long)(n0 + r) * bs_ + lc * 4);
    }
  };
  const int tx = tid % (BN / TN);
  const int ty = tid / (BN / TN);
  float acc[TM][TN];
#pragma unroll
  for (int i = 0; i < TM; i++)
#pragma unroll
    for (int j = 0; j < TN; j++) acc[i][j] = 0.0f;
  load(0);
  for (int kt = 0; kt < nt; ++kt) {
    __syncthreads();
#pragma unroll
    for (int p = 0; p < APASS; p++) {
      int r = lr + p * RPP;
      As[lc * 4 + 0][r] = pa[p].x; As[lc * 4 + 1][r] = pa[p].y;
      As[lc * 4 + 2][r] = pa[p].z; As[lc * 4 + 3][r] = pa[p].w;
    }
#pragma unroll
    for (int p = 0; p < BPASS; p++) {
      int r = lr + p * RPP;
      Bs[lc * 4 + 0][r] = pb[p].x; Bs[lc * 4 + 1][r] = pb[p].y;
      Bs[lc * 4 + 2][r] = pb[p].z; Bs[lc * 4 + 3][r] = pb[p].w;
    }
    __syncthreads();
    if (kt + 1 < nt) load(kt + 1);
#pragma unroll
    for (int k = 0; k < BKK; k++) {
      float a[TM], bfr[TN];
#pragma unroll
      for (int i = 0; i < TM; i++) a[i] = As[k][ty * TM + i];
#pragma unroll
      for (int j = 0; j < TN; j++) bfr[j] = Bs[k][tx * TN + j];
#pragma unroll
      for (int i = 0; i < TM; i++)
#pragma unroll
        for (int j = 0; j < TN; j++) acc[i][j] += a[i] * bfr[j];
    }
  }
#pragma unroll
  for (int i = 0; i < TM; i++) {
    const int m = m0 + ty * TM + i;
    const int n = n0 + tx * TN;
    float v[TN];
#pragma unroll
    for (int j = 0; j < TN; j++) {
      float a = acc[i][j];
      if (EPI == 0) {
        float s = e1[n + j] * 0.999995f;
        a = (a + e0[n + j]) * s + e2[n + j];
        a = fmaxf(a, 0.0f);
      } else {
        a = a + e0[n + j] + e1[n + j];
      }
      v[j] = a;
    }
    float4 o; o.x = v[0]; o.y = v[1]; o.z = v[2]; o.w = v[3];
    *(float4*)(C + (long long)m * ldc + n) = o;
  }
}

__global__ __launch_bounds__(256) void zs32_k(const float* __restrict__ sf,
                                              const float* __restrict__ Wg,
                                              float* __restrict__ zs)
{
  const int wave = threadIdx.x >> 6, lane = threadIdx.x & 63;
  const int row = blockIdx.x * 4 + wave;
  const float* s = sf + (long long)row * 512 + lane * 8;
  const float* w0 = Wg + lane * 8;
  const float* w1 = Wg + 2560 + lane * 8;
  float4 sa = *(const float4*)s, sb = *(const float4*)(s + 4);
  float4 a0 = *(const float4*)w0, b0 = *(const float4*)(w0 + 4);
  float4 a1 = *(const float4*)w1, b1 = *(const float4*)(w1 + 4);
  float z0 = sa.x * a0.x + sa.y * a0.y + sa.z * a0.z + sa.w * a0.w
           + sb.x * b0.x + sb.y * b0.y + sb.z * b0.z + sb.w * b0.w;
  float z1 = sa.x * a1.x + sa.y * a1.y + sa.z * a1.z + sa.w * a1.w
           + sb.x * b1.x + sb.y * b1.y + sb.z * b1.z + sb.w * b1.w;
#pragma unroll
  for (int off = 32; off > 0; off >>= 1) {
    z0 += __shfl_down(z0, off);
    z1 += __shfl_down(z1, off);
  }
  if (lane == 0) { zs[row * 2] = z0; zs[row * 2 + 1] = z1; }
}

__global__ __launch_bounds__(256) void step_upd32(
    const float* __restrict__ gl, const float* __restrict__ gs,
    const float* __restrict__ hl_o, const float* __restrict__ cl_o,
    const float* __restrict__ cs_o,
    float* __restrict__ hl_n, float* __restrict__ cl_n,
    float* __restrict__ hs_n, float* __restrict__ cs_n,
    const float* __restrict__ zs, const float* __restrict__ Wg,
    const float* __restrict__ bg, float* __restrict__ rout, int t)
{
  const int b = blockIdx.x, tid = threadIdx.x;
  __shared__ float red0[256], red1[256];
  __shared__ float shs[512], scs[512];
  __shared__ float rsh[2];
  float4 h4 = *(const float4*)(hl_o + (long long)b * 1024 + tid * 4);
  float4 c4 = *(const float4*)(cl_o + (long long)b * 1024 + tid * 4);
  float4 w0h = *(const float4*)(Wg + 512 + tid * 4);
  float4 w0c = *(const float4*)(Wg + 1536 + tid * 4);
  float4 w1h = *(const float4*)(Wg + 2560 + 512 + tid * 4);
  float4 w1c = *(const float4*)(Wg + 2560 + 1536 + tid * 4);
  red0[tid] = h4.x * w0h.x + h4.y * w0h.y + h4.z * w0h.z + h4.w * w0h.w
            + c4.x * w0c.x + c4.y * w0c.y + c4.z * w0c.z + c4.w * w0c.w;
  red1[tid] = h4.x * w1h.x + h4.y * w1h.y + h4.z * w1h.z + h4.w * w1h.w
            + c4.x * w1c.x + c4.y * w1c.y + c4.z * w1c.z + c4.w * w1c.w;
  {
    const float* gb = gs + (long long)b * 2048;
#pragma unroll
    for (int e = 0; e < 2; ++e) {
      const int n = tid * 2 + e;
      float gi = gb[n], gf = gb[512 + n], gg = gb[1024 + n], go = gb[1536 + n];
      float c2 = sigf(gf) * cs_o[b * 512 + n] + sigf(gi) * tanhf(gg);
      float h2 = sigf(go) * tanhf(c2);
      shs[n] = h2; scs[n] = c2;
      hs_n[b * 512 + n] = h2; cs_n[b * 512 + n] = c2;
    }
  }
  __syncthreads();
  for (int s = 128; s > 0; s >>= 1) {
    if (tid < s) { red0[tid] += red0[tid + s]; red1[tid] += red1[tid + s]; }
    __syncthreads();
  }
  if (tid == 0) {
    float z0 = red0[0] + zs[(b * 64 + t) * 2 + 0] + bg[0];
    float z1 = red1[0] + zs[(b * 64 + t) * 2 + 1] + bg[1];
    int hard = (z1 > z0) ? 1 : 0;
    rsh[0] = hard ? 0.0f : 1.0f; rsh[1] = hard ? 1.0f : 0.0f;
    rout[b * 2 + 0] = rsh[0]; rout[b * 2 + 1] = rsh[1];
  }
  __syncthreads();
  const float r0 = rsh[0], r1 = rsh[1];
  {
    const float* glb = gl + (long long)b * 4096;
    const int n = tid * 4;
    float4 gi4 = *(const float4*)(glb + n);
    float4 gf4 = *(const float4*)(glb + 1024 + n);
    float4 gg4 = *(const float4*)(glb + 2048 + n);
    float4 go4 = *(const float4*)(glb + 3072 + n);
    float4 co4 = *(const float4*)(cl_o + (long long)b * 1024 + n);
    float4 ho4 = *(const float4*)(hl_o + (long long)b * 1024 + n);
    float gi[4] = {gi4.x, gi4.y, gi4.z, gi4.w};
    float gf[4] = {gf4.x, gf4.y, gf4.z, gf4.w};
    float gg[4] = {gg4.x, gg4.y, gg4.z, gg4.w};
    float go[4] = {go4.x, go4.y, go4.z, go4.w};
    float co[4] = {co4.x, co4.y, co4.z, co4.w};
    float ho[4] = {ho4.x, ho4.y, ho4.z, ho4.w};
    float hv[4], cv[4];
#pragma unroll
    for (int e = 0; e < 4; ++e) {
      float cln = sigf(gf[e]) * co[e] + sigf(gi[e]) * tanhf(gg[e]);
      float hln = sigf(go[e]) * tanhf(cln);
      float ph = (n + e < 512) ? shs[n + e] : ho[e];
      float pc = (n + e < 512) ? scs[n + e] : co[e];
      hv[e] = r0 * hln + r1 * ph;
      cv[e] = r0 * cln + r1 * pc;
    }
    float4 hw = {hv[0], hv[1], hv[2], hv[3]};
    float4 cw = {cv[0], cv[1], cv[2], cv[3]};
    *(float4*)(hl_n + (long long)b * 1024 + n) = hw;
    *(float4*)(cl_n + (long long)b * 1024 + n) = cw;
  }
}

// ===========================================================================
extern "C" void kernel_launch(void* const* d_in, const int* in_sizes, int n_in,
                              void* d_out, int out_size, void* d_ws, size_t ws_size,
                              hipStream_t stream)
{
  const float* x     = (const float*)d_in[0];
  const float* xs    = (const float*)d_in[1];
  const float* W_p   = (const float*)d_in[2];
  const float* b_p   = (const float*)d_in[3];
  const float* g_p   = (const float*)d_in[4];
  const float* be_p  = (const float*)d_in[5];
  const float* W_s   = (const float*)d_in[6];
  const float* b_s   = (const float*)d_in[7];
  const float* g_s   = (const float*)d_in[8];
  const float* be_s  = (const float*)d_in[9];
  const float* Wih_l = (const float*)d_in[10];
  const float* Whh_l = (const float*)d_in[11];
  const float* bih_l = (const float*)d_in[12];
  const float* bhh_l = (const float*)d_in[13];
  const float* Wih_s = (const float*)d_in[14];
  const float* Whh_s = (const float*)d_in[15];
  const float* bih_s = (const float*)d_in[16];
  const float* bhh_s = (const float*)d_in[17];
  const float* W_g   = (const float*)d_in[18];
  const float* b_g   = (const float*)d_in[19];
  const float* W_c   = (const float*)d_in[20];
  const float* b_c   = (const float*)d_in[21];
  float* out = (float*)d_out;
  float* r_out = out + 61184;            // [64][256][2]

  const int BT = 16384;
  const size_t FIXEDB = 100794368ULL;
  const size_t CHUNKB = 12320768ULL;
  int Tp = 0;
  for (int T = 64; T >= 1; T >>= 1)
    if (FIXEDB + CHUNKB * (size_t)T + 65536 <= ws_size) { Tp = T; break; }

  if (Tp > 0) {
    char* base = (char*)d_ws;
    size_t off = 0;
    auto alloc = [&](size_t n) { void* p = base + off; off += (n + 255) & ~255ULL; return p; };
    f16* WpI[2]  = {(f16*)alloc(8388608),  (f16*)alloc(8388608)};
    f16* WsI[2]  = {(f16*)alloc(1310720),  (f16*)alloc(1310720)};
    f16* WilI[2] = {(f16*)alloc(20971520), (f16*)alloc(20971520)};
    f16* WisI[2] = {(f16*)alloc(2097152),  (f16*)alloc(2097152)};
    f16* WhlI[2] = {(f16*)alloc(8388608),  (f16*)alloc(8388608)};
    f16* WhsI[2] = {(f16*)alloc(2097152),  (f16*)alloc(2097152)};
    f16* hlI[2] = {(f16*)alloc(524288), (f16*)alloc(524288)};
    f16* hsI[2] = {(f16*)alloc(262144), (f16*)alloc(262144)};
    float* zs  = (float*)alloc(131072);
    float* hl[2] = {(float*)alloc(1048576), (float*)alloc(1048576)};
    float* cl[2] = {(float*)alloc(1048576), (float*)alloc(1048576)};
    float* hsb[2] = {(float*)alloc(524288), (float*)alloc(524288)};
    float* csb[2] = {(float*)alloc(524288), (float*)alloc(524288)};
    float* gates_l = (float*)alloc(4194304);
    float* gates_s = (float*)alloc(2097152);
    f16* xI[2]  = {(f16*)alloc(1048576ULL * Tp), (f16*)alloc(1048576ULL * Tp)};
    f16* xsI[2] = {(f16*)alloc(655360ULL * Tp),  (f16*)alloc(655360ULL * Tp)};
    f16* feI[2] = {(f16*)alloc(1048576ULL * Tp), (f16*)alloc(1048576ULL * Tp)};
    f16* sfI[2] = {(f16*)alloc(262144ULL * Tp),  (f16*)alloc(262144ULL * Tp)};
    float* GxlC = (float*)alloc(4194304ULL * Tp);
    float* GxsC = (float*)alloc(2097152ULL * Tp);

    // one-time weight packs
    pack_img<<<2048, 256, 0, stream>>>(W_p,   2048, 64, 0, 0, WpI[0],  WpI[1],  524288);
    pack_img<<<320,  256, 0, stream>>>(W_s,   1280, 40, 0, 0, WsI[0],  WsI[1],  81920);
    pack_img<<<5120, 256, 0, stream>>>(Wih_l, 2560, 80, 0, 0, WilI[0], WilI[1], 1310720);
    pack_img<<<512,  256, 0, stream>>>(Wih_s, 512,  16, 0, 0, WisI[0], WisI[1], 131072);
    pack_img<<<2048, 256, 0, stream>>>(Whh_l, 1024, 32, 0, 0, WhlI[0], WhlI[1], 524288);
    pack_img<<<512,  256, 0, stream>>>(Whh_s, 512,  16, 0, 0, WhsI[0], WhsI[1], 131072);

    hipMemsetAsync(hl[0], 0, 1048576, stream);
    hipMemsetAsync(cl[0], 0, 1048576, stream);
    hipMemsetAsync(hsb[0], 0, 524288, stream);
    hipMemsetAsync(csb[0], 0, 524288, stream);
    hipMemsetAsync(hlI[0], 0, 524288, stream);
    hipMemsetAsync(hlI[1], 0, 524288, stream);
    hipMemsetAsync(hsI[0], 0, 262144, stream);
    hipMemsetAsync(hsI[1], 0, 262144, stream);

    const int rows = 256 * Tp;             // chunk rows (time-major)
    const int gA2 = Tp;                    // 256-row tiles
    const int bx = rows;                   // pack-x blocks; pack-xs = rows*5/8
    for (int t0 = 0; t0 < 64; t0 += Tp) {
      // merged input packs (x + xs)
      pack2_k<<<bx + rows * 5 / 8, 256, 0, stream>>>(
          bx, x, xs, t0, xI[0], xI[1], xsI[0], xsI[1]);
      // sfeats chunk -> sf image (256^2, gB=2)
      gmm256w<0><<<gA2 * 2, 512, 0, stream>>>(
          gA2, 2, 0,
          xsI[0], xsI[1], 40, nullptr, nullptr, 0,
          WsI[0], WsI[1], 40,
          nullptr, 0, sfI[0], sfI[1], 16, b_s, g_s, be_s);
      zs_img_k<<<rows / 4, 256, 0, stream>>>(sfI[0], sfI[1], W_g, zs, t0);
      // fe (image out) and Gx_s (f32 out) merged: 2*gA2*8 blocks
      fegxs_k<<<gA2 * 16, 512, 0, stream>>>(
          gA2,
          xI[0], xI[1], WpI[0], WpI[1], feI[0], feI[1], b_p, g_p, be_p,
          sfI[0], sfI[1], WisI[0], WisI[1], GxsC, bih_s, bhh_s);
      // Gx_l = [fe|sf] @ Wih_l^T + bih_l + bhh_l  (256^2, cohort)
      gmm256w<1><<<gA2 * 16, 512, 0, stream>>>(
          gA2, 16, 1,
          feI[0], feI[1], 64, sfI[0], sfI[1], 16,
          WilI[0], WilI[1], 80,
          GxlC, 4096, nullptr, nullptr, 0, bih_l, bhh_l, nullptr);

      for (int tt = 0; tt < Tp; ++tt) {
        const int t = t0 + tt;
        const int o = t & 1, nw = o ^ 1;
        stepg_k<<<96, 256, 0, stream>>>(
            hlI[0], hlI[1], hsI[0], hsI[1],
            WhlI[0], WhlI[1], WhsI[0], WhsI[1],
            GxlC + (long long)tt * 256 * 4096, GxsC + (long long)tt * 256 * 2048,
            gates_l, gates_s);
        step_upd<<<256, 256, 0, stream>>>(
            gates_l, gates_s, hl[o], cl[o], csb[o],
            hl[nw], cl[nw], hsb[nw], csb[nw],
            hlI[0], hlI[1], hsI[0], hsI[1],
            zs, W_g, b_g, r_out + (long long)t * 512, t);
      }
    }
    logits_k<<<256, 256, 0, stream>>>(hl[0], W_c, b_c, out);
    return;
  }

  // ---------------- all-f32 fallback (tiny workspace) ----------------
  float* ws = (float*)d_ws;
  size_t offf = 0;
  auto allocf = [&](size_t n) { float* p = ws + offf; offf += n; return p; };
  float* feats   = allocf((size_t)BT * 2048);
  float* sfeats  = allocf((size_t)BT * 512);
  float* zs      = allocf((size_t)BT * 2);
  float* gates_l = allocf((size_t)256 * 4096);
  float* gates_s = allocf((size_t)256 * 2048);
  float* hl[2] = { allocf(256 * 1024), allocf(256 * 1024) };
  float* cl[2] = { allocf(256 * 1024), allocf(256 * 1024) };
  float* hsb[2] = { allocf(256 * 512),  allocf(256 * 512) };
  float* csb[2] = { allocf(256 * 512),  allocf(256 * 512) };

  hipMemsetAsync(hl[0], 0, 256 * 1024 * sizeof(float), stream);
  hipMemsetAsync(cl[0], 0, 256 * 1024 * sizeof(float), stream);
  hipMemsetAsync(hsb[0], 0, 256 * 512 * sizeof(float), stream);
  hipMemsetAsync(csb[0], 0, 256 * 512 * sizeof(float), stream);

  gemm_nt<128, 64, 8, 4, 0><<<dim3(BT / 128, 2048 / 64), 256, 0, stream>>>(
      BT, 2048, x, 2048, W_p, 2048, 2048,
      nullptr, 0, nullptr, 0, 0, nullptr, 0, nullptr, 0, 0,
      feats, 2048, b_p, g_p, be_p);
  gemm_nt<128, 64, 8, 4, 0><<<dim3(BT / 128, 512 / 64), 256, 0, stream>>>(
      BT, 512, xs, 1280, W_s, 1280, 1280,
      nullptr, 0, nullptr, 0, 0, nullptr, 0, nullptr, 0, 0,
      sfeats, 512, b_s, g_s, be_s);
  zs32_k<<<BT / 4, 256, 0, stream>>>(sfeats, W_g, zs);

  for (int t = 0; t < 64; ++t) {
    const int o = t & 1, nw = o ^ 1;
    gemm_nt<64, 64, 4, 4, 1><<<dim3(4, 2048 / 64), 256, 0, stream>>>(
        256, 2048, sfeats + (long long)t * 512, 64LL * 512, Wih_s, 512, 512,
        hsb[o], 512, Whh_s, 512, 512, nullptr, 0, nullptr, 0, 0,
        gates_s, 2048, bih_s, bhh_s, nullptr);
    gemm_nt<64, 64, 4, 4, 1><<<dim3(4, 4096 / 64), 256, 0, stream>>>(
        256, 4096, feats + (long long)t * 2048, 64LL * 2048, Wih_l, 2560, 2048,
        sfeats + (long long)t * 512, 64LL * 512, Wih_l + 2048, 2560, 512,
        hl[o], 1024, Whh_l, 1024, 1024,
        gates_l, 4096, bih_l, bhh_l, nullptr);
    step_upd32<<<256, 256, 0, stream>>>(
        gates_l, gates_s, hl[o], cl[o], csb[o],
        hl[nw], cl[nw], hsb[nw], csb[nw],
        zs, W_g, b_g, r_out + (long long)t * 512, t);
  }
  logits_k<<<256, 256, 0, stream>>>(hl[0], W_c, b_c, out);
}

// Round 12
// 3973.677 us; speedup vs baseline: 1.0439x; 1.0439x over previous
//
#include <hip/hip_runtime.h>
#include <math.h>

// ---------------------------------------------------------------------------
// LiteEval gated dual-LSTM.  Round 12 = consolidation on the measured optimum
// (R5 configuration, 3934 us; all 7 subsequent structural variants regressed).
//  * Big per-chunk GEMMs: 256x256-tile 8-wave (512 thr) split-f16 MFMA,
//    2-phase double-buffer, fragment-linear LDS (128 KB), plain 2D grids.
//  * Images (fragment-contiguous operand layouts): every global_load_lds(16B)
//    reads 1KB contiguous.
//  * pack_h2 fused into step_upd (h-state images written in the update).
//  * Sequential stepg on the 128x128 gcore.
//  * Fallback: all-f32 path for tiny workspace.
// ---------------------------------------------------------------------------

typedef _Float16 f16;
typedef _Float16 f16x4 __attribute__((ext_vector_type(4)));
typedef _Float16 f16x8 __attribute__((ext_vector_type(8)));
typedef float f32x4 __attribute__((ext_vector_type(4)));

__device__ __forceinline__ float sigf(float x) { return 1.0f / (1.0f + expf(-x)); }

__device__ __forceinline__ void gload16(const f16* g, f16* l) {
  __builtin_amdgcn_global_load_lds((const __attribute__((address_space(1))) void*)g,
                                   (__attribute__((address_space(3))) void*)l, 16, 0, 0);
}

// ---------------------------------------------------------------------------
// pack f32 [R][C] row-major (optional chunk time-major row remap) -> image
// image elem (row = p*128 + j*16 + (lane&15), k = kt*32 + (lane>>4)*8 + e)
// at f16 offset ((p*KT + kt)*8 + j)*512 + lane*8 + e           (KT = K/32)
__global__ __launch_bounds__(256) void pack_img(const float* __restrict__ src,
    int C, int KT, int t0, int map, f16* __restrict__ dh, f16* __restrict__ dl,
    int slots)
{
  int gid = blockIdx.x * 256 + threadIdx.x;
  if (gid >= slots) return;
  int lane = gid & 63;
  int j = (gid >> 6) & 7;
  int pk = gid >> 9;
  int p = pk / KT, kt = pk - p * KT;
  int r = p * 128 + j * 16 + (lane & 15);
  int rg = map ? (((r & 255) << 6) + t0 + (r >> 8)) : r;
  int c = kt * 32 + (lane >> 4) * 8;
  const float* s = src + (long long)rg * C + c;
  float4 v0 = *(const float4*)s, v1 = *(const float4*)(s + 4);
  f16x8 h, l;
  h[0]=(f16)v0.x; l[0]=(f16)(v0.x-(float)h[0]);
  h[1]=(f16)v0.y; l[1]=(f16)(v0.y-(float)h[1]);
  h[2]=(f16)v0.z; l[2]=(f16)(v0.z-(float)h[2]);
  h[3]=(f16)v0.w; l[3]=(f16)(v0.w-(float)h[3]);
  h[4]=(f16)v1.x; l[4]=(f16)(v1.x-(float)h[4]);
  h[5]=(f16)v1.y; l[5]=(f16)(v1.y-(float)h[5]);
  h[6]=(f16)v1.z; l[6]=(f16)(v1.z-(float)h[6]);
  h[7]=(f16)v1.w; l[7]=(f16)(v1.w-(float)h[7]);
  *(f16x8*)(dh + (long long)gid * 8) = h;
  *(f16x8*)(dl + (long long)gid * 8) = l;
}

// ---------------------------------------------------------------------------
// 256x256-tile split-f16 MFMA GEMM on images. 512 threads = 8 waves (2M x 4N).
// BK=32; LDS: 2 x {Ah,Al,Bh,Bl} x 16KB = 128 KB; 2-phase double buffer.
// A: up to 2 K-segments of images; B: one image.  nt = KT0+KT1 (= KTB).
// EPI 0: relu((v+e0)*e1*s+e2) -> image hi/lo out (Ch,Cl,KTout) via LDS bounce
// EPI 1: v + e0[col] + e1[col] -> f32 row-major C (ldc)
template <int EPI>
__global__ __launch_bounds__(512, 1) void gmm256(
    const f16* __restrict__ Ah0, const f16* __restrict__ Al0, int KT0,
    const f16* __restrict__ Ah1, const f16* __restrict__ Al1, int KT1,
    const f16* __restrict__ Bh, const f16* __restrict__ Bl, int KTB,
    float* __restrict__ C, int ldc,
    f16* __restrict__ Ch, f16* __restrict__ Cl, int KTout,
    const float* __restrict__ e0, const float* __restrict__ e1,
    const float* __restrict__ e2)
{
  __shared__ __align__(16) char smem[131072];
  f16 (*sm)[4][8192] = (f16 (*)[4][8192])smem;   // [buf][Ah,Al,Bh,Bl][...]
  const int tid = threadIdx.x;
  const int w = tid >> 6, lane = tid & 63;
  const int wr = w >> 2, wc = w & 3;             // 2 M-waves x 4 N-waves
  const int fr = lane & 15, fq = lane >> 4;
  const int pA = blockIdx.y, pB = blockIdx.x;
  const int sarr = w >> 1, shalf = w & 1;        // staging: array, panel half

  const int nt = KT0 + KT1;

  auto stage = [&](int buf, int kt) {
    const f16* base;
    if (sarr >= 2) {
      base = ((sarr == 2) ? Bh : Bl) + ((long long)(pB * 2 + shalf) * KTB + kt) * 4096;
    } else if (kt < KT0) {
      base = ((sarr == 0) ? Ah0 : Al0) + ((long long)(pA * 2 + shalf) * KT0 + kt) * 4096;
    } else {
      base = ((sarr == 0) ? Ah1 : Al1) + ((long long)(pA * 2 + shalf) * KT1 + (kt - KT0)) * 4096;
    }
    f16* dst = &sm[buf][sarr][shalf * 4096];
#pragma unroll
    for (int j = 0; j < 8; ++j)
      gload16(base + j * 512 + lane * 8, dst + j * 512);
  };

  f32x4 acc[8][4];
#pragma unroll
  for (int m = 0; m < 8; ++m)
#pragma unroll
    for (int n = 0; n < 4; ++n) acc[m][n] = (f32x4){0.f, 0.f, 0.f, 0.f};

  stage(0, 0);
  __syncthreads();
  int cur = 0;
  for (int kt = 0; kt < nt; ++kt) {
    if (kt + 1 < nt) stage(cur ^ 1, kt + 1);     // prefetch next K-tile
    f16x8 bh_[4], bl_[4];
#pragma unroll
    for (int n = 0; n < 4; ++n) {
      bh_[n] = *(const f16x8*)&sm[cur][2][(wc * 4 + n) * 512 + lane * 8];
      bl_[n] = *(const f16x8*)&sm[cur][3][(wc * 4 + n) * 512 + lane * 8];
    }
#pragma unroll
    for (int m = 0; m < 8; ++m) {
      f16x8 ah = *(const f16x8*)&sm[cur][0][wr * 4096 + m * 512 + lane * 8];
      f16x8 al = *(const f16x8*)&sm[cur][1][wr * 4096 + m * 512 + lane * 8];
#pragma unroll
      for (int n = 0; n < 4; ++n) {
        acc[m][n] = __builtin_amdgcn_mfma_f32_16x16x32_f16(ah, bh_[n], acc[m][n], 0, 0, 0);
        acc[m][n] = __builtin_amdgcn_mfma_f32_16x16x32_f16(ah, bl_[n], acc[m][n], 0, 0, 0);
        acc[m][n] = __builtin_amdgcn_mfma_f32_16x16x32_f16(al, bh_[n], acc[m][n], 0, 0, 0);
      }
    }
    __syncthreads();                             // drains prefetch; guards dbuf
    cur ^= 1;
  }

  if (EPI == 1) {
#pragma unroll
    for (int m = 0; m < 8; ++m) {
#pragma unroll
      for (int n = 0; n < 4; ++n) {
        const int col = pB * 256 + wc * 64 + n * 16 + fr;
        const float add = e0[col] + e1[col];
#pragma unroll
        for (int r = 0; r < 4; ++r) {
          const int row = pA * 256 + wr * 128 + m * 16 + fq * 4 + r;
          C[(long long)row * ldc + col] = acc[m][n][r] + add;
        }
      }
    }
  } else {
    // BN+ReLU -> image out via quarter-tile (64-row) f32 LDS bounce
    float* cb = (float*)smem;
    const int CBLD = 260;
    for (int q = 0; q < 4; ++q) {
      __syncthreads();
      if (wr == (q >> 1)) {
#pragma unroll
        for (int mm = 0; mm < 4; ++mm) {
          const int m = (q & 1) * 4 + mm;
#pragma unroll
          for (int n = 0; n < 4; ++n) {
            const int colL = wc * 64 + n * 16 + fr;
            const int colG = pB * 256 + colL;
            const float p0 = e0[colG], p1 = e1[colG] * 0.99999500003750f, p2 = e2[colG];
#pragma unroll
            for (int r = 0; r < 4; ++r) {
              const int rq = mm * 16 + fq * 4 + r;
              cb[rq * CBLD + colL] = fmaxf((acc[m][n][r] + p0) * p1 + p2, 0.f);
            }
          }
        }
      }
      __syncthreads();
      // readout: wave w handles k-tile ktl=w; lanes: fr_o row, fq_o k-sub
      const int ktl = w;
      const int p_out = pA * 2 + (q >> 1);
#pragma unroll
      for (int jp = 0; jp < 4; ++jp) {
        const int rL = jp * 16 + fr;
        const float* s = &cb[rL * CBLD + ktl * 32 + fq * 8];
        float4 v0 = *(const float4*)s, v1 = *(const float4*)(s + 4);
        float vv[8] = {v0.x, v0.y, v0.z, v0.w, v1.x, v1.y, v1.z, v1.w};
        f16x8 h, l;
#pragma unroll
        for (int e = 0; e < 8; ++e) {
          h[e] = (f16)vv[e]; l[e] = (f16)(vv[e] - (float)h[e]);
        }
        const int j_img = (q & 1) * 4 + jp;
        const long long o =
            (((long long)p_out * KTout + (pB * 8 + ktl)) * 8 + j_img) * 512 + lane * 8;
        *(f16x8*)(Ch + o) = h;
        *(f16x8*)(Cl + o) = l;
      }
    }
  }
}

// ---------------------------------------------------------------------------
// 128x128-tile split-MFMA gcore (EPI 2: v + G) — used for per-step recurrent
// GEMM only (M=256, operands L2/L3-resident).
__device__ __forceinline__ void gcore_step(int pA, int pB,
    const f16* __restrict__ Ah0, const f16* __restrict__ Al0, int KT0,
    const f16* __restrict__ Bh, const f16* __restrict__ Bl,
    float* __restrict__ C, int ldc, const float* __restrict__ G)
{
  __shared__ __align__(16) char smem[65536];
  f16 (*sm)[4][4096] = (f16 (*)[4][4096])smem;
  const int tid = threadIdx.x;
  const int w = tid >> 6, lane = tid & 63;
  const int wr = w >> 1, wc = w & 1;
  const int fr = lane & 15, fq = lane >> 4;

  const f16* aH = Ah0 + (long long)pA * KT0 * 4096;
  const f16* aL = Al0 + (long long)pA * KT0 * 4096;
  const f16* bH = Bh + (long long)pB * KT0 * 4096;
  const f16* bL = Bl + (long long)pB * KT0 * 4096;

  auto stage = [&](int buf, int kt) {
    const f16* src;
    if (w == 0)      src = aH + (long long)kt * 4096;
    else if (w == 1) src = aL + (long long)kt * 4096;
    else if (w == 2) src = bH + (long long)kt * 4096;
    else             src = bL + (long long)kt * 4096;
    f16* dst = &sm[buf][w][0];
#pragma unroll
    for (int j = 0; j < 8; ++j)
      gload16(src + j * 512 + lane * 8, dst + j * 512);
  };

  f32x4 acc[4][4];
#pragma unroll
  for (int m = 0; m < 4; ++m)
#pragma unroll
    for (int n = 0; n < 4; ++n) acc[m][n] = (f32x4){0.f, 0.f, 0.f, 0.f};

  stage(0, 0);
  __syncthreads();
  int cur = 0;
  for (int kt = 0; kt < KT0; ++kt) {
    if (kt + 1 < KT0) stage(cur ^ 1, kt + 1);
    f16x8 bhx[4], blx[4];
#pragma unroll
    for (int n = 0; n < 4; ++n) {
      bhx[n] = *(const f16x8*)&sm[cur][2][(wc * 4 + n) * 512 + lane * 8];
      blx[n] = *(const f16x8*)&sm[cur][3][(wc * 4 + n) * 512 + lane * 8];
    }
#pragma unroll
    for (int m = 0; m < 4; ++m) {
      f16x8 ah = *(const f16x8*)&sm[cur][0][(wr * 4 + m) * 512 + lane * 8];
      f16x8 al = *(const f16x8*)&sm[cur][1][(wr * 4 + m) * 512 + lane * 8];
#pragma unroll
      for (int n = 0; n < 4; ++n) {
        acc[m][n] = __builtin_amdgcn_mfma_f32_16x16x32_f16(ah, bhx[n], acc[m][n], 0, 0, 0);
        acc[m][n] = __builtin_amdgcn_mfma_f32_16x16x32_f16(ah, blx[n], acc[m][n], 0, 0, 0);
        acc[m][n] = __builtin_amdgcn_mfma_f32_16x16x32_f16(al, bhx[n], acc[m][n], 0, 0, 0);
      }
    }
    __syncthreads();
    cur ^= 1;
  }

#pragma unroll
  for (int m = 0; m < 4; ++m) {
#pragma unroll
    for (int n = 0; n < 4; ++n) {
      const int col = pB * 128 + wc * 64 + n * 16 + fr;
#pragma unroll
      for (int r = 0; r < 4; ++r) {
        const int row = pA * 128 + wr * 64 + m * 16 + fq * 4 + r;
        const long long idx = (long long)row * ldc + col;
        C[idx] = acc[m][n][r] + G[idx];
      }
    }
  }
}

// routed per-step recurrent GEMM: y<32 -> large (N=4096,K=1024), else small
__global__ __launch_bounds__(256) void stepg_k(
    const f16* __restrict__ hlh, const f16* __restrict__ hll,
    const f16* __restrict__ hsh, const f16* __restrict__ hsl,
    const f16* __restrict__ Whl_h, const f16* __restrict__ Whl_l,
    const f16* __restrict__ Whs_h, const f16* __restrict__ Whs_l,
    const float* __restrict__ Gl, const float* __restrict__ Gs,
    float* __restrict__ gl, float* __restrict__ gs)
{
  if (blockIdx.y < 32)
    gcore_step(blockIdx.x, blockIdx.y, hlh, hll, 32,
               Whl_h, Whl_l, gl, 4096, Gl);
  else
    gcore_step(blockIdx.x, blockIdx.y - 32, hsh, hsl, 16,
               Whs_h, Whs_l, gs, 2048, Gs);
}

// zs from sf image (chunk): zs[bt,g] = sfeats[bt,:512] . W_g[g,:512]
__global__ __launch_bounds__(256) void zs_img_k(const f16* __restrict__ sfh,
    const f16* __restrict__ sfl, const float* __restrict__ Wg,
    float* __restrict__ zs, int t0)
{
  const int wv = threadIdx.x >> 6, lane = threadIdx.x & 63;
  const int rr = blockIdx.x * 4 + wv;
  const int p = rr >> 7, j = (rr >> 4) & 7, fr = rr & 15;
  const int kt = lane >> 2, fq = lane & 3;
  const long long a = (((long long)p * 16 + kt) * 8 + j) * 512 + (fq * 16 + fr) * 8;
  f16x8 h8 = *(const f16x8*)(sfh + a);
  f16x8 l8 = *(const f16x8*)(sfl + a);
  const int k0 = kt * 32 + fq * 8;
  float z0 = 0.f, z1 = 0.f;
#pragma unroll
  for (int i = 0; i < 8; ++i) {
    float s = (float)h8[i] + (float)l8[i];
    z0 += s * Wg[k0 + i]; z1 += s * Wg[2560 + k0 + i];
  }
#pragma unroll
  for (int off = 32; off > 0; off >>= 1) {
    z0 += __shfl_down(z0, off);
    z1 += __shfl_down(z1, off);
  }
  if (lane == 0) {
    const int bt = ((rr & 255) << 6) + t0 + (rr >> 8);
    zs[bt * 2] = z0; zs[bt * 2 + 1] = z1;
  }
}

// fused per-step update: gate argmax + small-cell update + large-cell blend +
// write the NEW h-state images.
__global__ __launch_bounds__(256) void step_upd(
    const float* __restrict__ gl, const float* __restrict__ gs,
    const float* __restrict__ hl_o, const float* __restrict__ cl_o,
    const float* __restrict__ cs_o,
    float* __restrict__ hl_n, float* __restrict__ cl_n,
    float* __restrict__ hs_n, float* __restrict__ cs_n,
    f16* __restrict__ hlIh, f16* __restrict__ hlIl,
    f16* __restrict__ hsIh, f16* __restrict__ hsIl,
    const float* __restrict__ zs, const float* __restrict__ Wg,
    const float* __restrict__ bg, float* __restrict__ rout, int t)
{
  const int b = blockIdx.x, tid = threadIdx.x;
  __shared__ float red0[256], red1[256];
  __shared__ float shs[512], scs[512];
  __shared__ float rsh[2];

  const int pb = b >> 7, jb = (b >> 4) & 7, frb = b & 15;

  float4 h4 = *(const float4*)(hl_o + (long long)b * 1024 + tid * 4);
  float4 c4 = *(const float4*)(cl_o + (long long)b * 1024 + tid * 4);
  float4 w0h = *(const float4*)(Wg + 512 + tid * 4);
  float4 w0c = *(const float4*)(Wg + 1536 + tid * 4);
  float4 w1h = *(const float4*)(Wg + 2560 + 512 + tid * 4);
  float4 w1c = *(const float4*)(Wg + 2560 + 1536 + tid * 4);
  red0[tid] = h4.x * w0h.x + h4.y * w0h.y + h4.z * w0h.z + h4.w * w0h.w
            + c4.x * w0c.x + c4.y * w0c.y + c4.z * w0c.z + c4.w * w0c.w;
  red1[tid] = h4.x * w1h.x + h4.y * w1h.y + h4.z * w1h.z + h4.w * w1h.w
            + c4.x * w1c.x + c4.y * w1c.y + c4.z * w1c.z + c4.w * w1c.w;

  {
    const float* gb = gs + (long long)b * 2048;
#pragma unroll
    for (int e = 0; e < 2; ++e) {
      const int n = tid * 2 + e;
      float gi = gb[n], gf = gb[512 + n], gg = gb[1024 + n], go = gb[1536 + n];
      float c2 = sigf(gf) * cs_o[b * 512 + n] + sigf(gi) * tanhf(gg);
      float h2 = sigf(go) * tanhf(c2);
      shs[n] = h2; scs[n] = c2;
      hs_n[b * 512 + n] = h2; cs_n[b * 512 + n] = c2;
      // hs image (KT=16)
      const int kt = n >> 5, fqn = (n >> 3) & 3, en = n & 7;
      const long long o = (((long long)pb * 16 + kt) * 8 + jb) * 512
                        + (fqn * 16 + frb) * 8 + en;
      f16 hh = (f16)h2;
      hsIh[o] = hh; hsIl[o] = (f16)(h2 - (float)hh);
    }
  }
  __syncthreads();
  for (int s = 128; s > 0; s >>= 1) {
    if (tid < s) { red0[tid] += red0[tid + s]; red1[tid] += red1[tid + s]; }
    __syncthreads();
  }
  if (tid == 0) {
    float z0 = red0[0] + zs[(b * 64 + t) * 2 + 0] + bg[0];
    float z1 = red1[0] + zs[(b * 64 + t) * 2 + 1] + bg[1];
    int hard = (z1 > z0) ? 1 : 0;   // jnp.argmax ties -> 0
    rsh[0] = hard ? 0.0f : 1.0f; rsh[1] = hard ? 1.0f : 0.0f;
    rout[b * 2 + 0] = rsh[0]; rout[b * 2 + 1] = rsh[1];
  }
  __syncthreads();
  const float r0 = rsh[0], r1 = rsh[1];

  {
    const float* glb = gl + (long long)b * 4096;
    const int n = tid * 4;
    float4 gi4 = *(const float4*)(glb + n);
    float4 gf4 = *(const float4*)(glb + 1024 + n);
    float4 gg4 = *(const float4*)(glb + 2048 + n);
    float4 go4 = *(const float4*)(glb + 3072 + n);
    float4 co4 = *(const float4*)(cl_o + (long long)b * 1024 + n);
    float4 ho4 = *(const float4*)(hl_o + (long long)b * 1024 + n);
    float gi[4] = {gi4.x, gi4.y, gi4.z, gi4.w};
    float gf[4] = {gf4.x, gf4.y, gf4.z, gf4.w};
    float gg[4] = {gg4.x, gg4.y, gg4.z, gg4.w};
    float go[4] = {go4.x, go4.y, go4.z, go4.w};
    float co[4] = {co4.x, co4.y, co4.z, co4.w};
    float ho[4] = {ho4.x, ho4.y, ho4.z, ho4.w};
    float hv[4], cv[4];
    f16x4 ih, il;
#pragma unroll
    for (int e = 0; e < 4; ++e) {
      float cln = sigf(gf[e]) * co[e] + sigf(gi[e]) * tanhf(gg[e]);
      float hln = sigf(go[e]) * tanhf(cln);
      float ph = (n + e < 512) ? shs[n + e] : ho[e];
      float pc = (n + e < 512) ? scs[n + e] : co[e];
      hv[e] = r0 * hln + r1 * ph;
      cv[e] = r0 * cln + r1 * pc;
      ih[e] = (f16)hv[e]; il[e] = (f16)(hv[e] - (float)ih[e]);
    }
    float4 hw = {hv[0], hv[1], hv[2], hv[3]};
    float4 cw = {cv[0], cv[1], cv[2], cv[3]};
    *(float4*)(hl_n + (long long)b * 1024 + n) = hw;
    *(float4*)(cl_n + (long long)b * 1024 + n) = cw;
    // hl image (KT=32): n..n+3 share kt,fq; e base = n&7 (0 or 4)
    const int kt = n >> 5, fqn = (n >> 3) & 3, en = n & 7;
    const long long o = (((long long)pb * 32 + kt) * 8 + jb) * 512
                      + (fqn * 16 + frb) * 8 + en;
    *(f16x4*)(hlIh + o) = ih;
    *(f16x4*)(hlIl + o) = il;
  }
}

// logits = h_l @ W_c^T + b_c
__global__ __launch_bounds__(256) void logits_k(const float* __restrict__ hl,
                                                const float* __restrict__ Wc,
                                                const float* __restrict__ bc,
                                                float* __restrict__ out)
{
  __shared__ float hsd[1024];
  const int b = blockIdx.x, tid = threadIdx.x;
  *(float4*)(hsd + tid * 4) = *(const float4*)(hl + (long long)b * 1024 + tid * 4);
  __syncthreads();
  if (tid < 239) {
    const float* w = Wc + (long long)tid * 1024;
    float s = 0.0f;
    for (int k = 0; k < 1024; k += 4) {
      float4 wv = *(const float4*)(w + k);
      s += hsd[k] * wv.x + hsd[k + 1] * wv.y + hsd[k + 2] * wv.z + hsd[k + 3] * wv.w;
    }
    out[(long long)b * 239 + tid] = s + bc[tid];
  }
}

// ===========================================================================
// all-f32 fallback (tiny workspace) — Round-1 proven path
#define BKK 32
template <int BM, int BN, int TM, int TN, int EPI>
__global__ __launch_bounds__(256) void gemm_nt(
    int M, int N,
    const float* __restrict__ A0, long long as0, const float* __restrict__ B0, long long bs0, int K0,
    const float* __restrict__ A1, long long as1, const float* __restrict__ B1, long long bs1, int K1,
    const float* __restrict__ A2, long long as2, const float* __restrict__ B2, long long bs2, int K2,
    float* __restrict__ C, long long ldc,
    const float* __restrict__ e0, const float* __restrict__ e1, const float* __restrict__ e2)
{
  __shared__ float As[BKK][BM + 4];
  __shared__ float Bs[BKK][BN + 4];
  const int tid = threadIdx.x;
  const int m0 = blockIdx.x * BM;
  const int n0 = blockIdx.y * BN;
  constexpr int C4 = BKK / 4;
  constexpr int RPP = 256 / C4;
  constexpr int APASS = BM / RPP;
  constexpr int BPASS = BN / RPP;
  const int lr = tid / C4;
  const int lc = tid % C4;
  float4 pa[APASS], pb[BPASS];
  const int nt = (K0 + K1 + K2) / BKK;
  auto load = [&](int kt) {
    const int kg = kt * BKK;
    const float* ap; long long as_; const float* bp; long long bs_;
    if (kg < K0)           { ap = A0 + kg;          as_ = as0; bp = B0 + kg;          bs_ = bs0; }
    else if (kg < K0 + K1) { int kl = kg - K0;      ap = A1 + kl; as_ = as1; bp = B1 + kl; bs_ = bs1; }
    else                   { int kl = kg - K0 - K1; ap = A2 + kl; as_ = as2; bp = B2 + kl; bs_ = bs2; }
#pragma unroll
    for (int p = 0; p < APASS; p++) {
      int r = lr + p * RPP;
      pa[p] = *(const float4*)(ap + (long long)(m0 + r) * as_ + lc * 4);
    }
#pragma unroll
    for (int p = 0; p < BPASS; p++) {
      int r = lr + p * RPP;
      pb[p] = *(const float4*)(bp + (long long)(n0 + r) * bs_ + lc * 4);
    }
  };
  const int tx = tid % (BN / TN);
  const int ty = tid / (BN / TN);
  float acc[TM][TN];
#pragma unroll
  for (int i = 0; i < TM; i++)
#pragma unroll
    for (int j = 0; j < TN; j++) acc[i][j] = 0.0f;
  load(0);
  for (int kt = 0; kt < nt; ++kt) {
    __syncthreads();
#pragma unroll
    for (int p = 0; p < APASS; p++) {
      int r = lr + p * RPP;
      As[lc * 4 + 0][r] = pa[p].x; As[lc * 4 + 1][r] = pa[p].y;
      As[lc * 4 + 2][r] = pa[p].z; As[lc * 4 + 3][r] = pa[p].w;
    }
#pragma unroll
    for (int p = 0; p < BPASS; p++) {
      int r = lr + p * RPP;
      Bs[lc * 4 + 0][r] = pb[p].x; Bs[lc * 4 + 1][r] = pb[p].y;
      Bs[lc * 4 + 2][r] = pb[p].z; Bs[lc * 4 + 3][r] = pb[p].w;
    }
    __syncthreads();
    if (kt + 1 < nt) load(kt + 1);
#pragma unroll
    for (int k = 0; k < BKK; k++) {
      float a[TM], bfr[TN];
#pragma unroll
      for (int i = 0; i < TM; i++) a[i] = As[k][ty * TM + i];
#pragma unroll
      for (int j = 0; j < TN; j++) bfr[j] = Bs[k][tx * TN + j];
#pragma unroll
      for (int i = 0; i < TM; i++)
#pragma unroll
        for (int j = 0; j < TN; j++) acc[i][j] += a[i] * bfr[j];
    }
  }
#pragma unroll
  for (int i = 0; i < TM; i++) {
    const int m = m0 + ty * TM + i;
    const int n = n0 + tx * TN;
    float v[TN];
#pragma unroll
    for (int j = 0; j < TN; j++) {
      float a = acc[i][j];
      if (EPI == 0) {
        float s = e1[n + j] * 0.999995f;
        a = (a + e0[n + j]) * s + e2[n + j];
        a = fmaxf(a, 0.0f);
      } else {
        a = a + e0[n + j] + e1[n + j];
      }
      v[j] = a;
    }
    float4 o; o.x = v[0]; o.y = v[1]; o.z = v[2]; o.w = v[3];
    *(float4*)(C + (long long)m * ldc + n) = o;
  }
}

__global__ __launch_bounds__(256) void zs32_k(const float* __restrict__ sf,
                                              const float* __restrict__ Wg,
                                              float* __restrict__ zs)
{
  const int wave = threadIdx.x >> 6, lane = threadIdx.x & 63;
  const int row = blockIdx.x * 4 + wave;
  const float* s = sf + (long long)row * 512 + lane * 8;
  const float* w0 = Wg + lane * 8;
  const float* w1 = Wg + 2560 + lane * 8;
  float4 sa = *(const float4*)s, sb = *(const float4*)(s + 4);
  float4 a0 = *(const float4*)w0, b0 = *(const float4*)(w0 + 4);
  float4 a1 = *(const float4*)w1, b1 = *(const float4*)(w1 + 4);
  float z0 = sa.x * a0.x + sa.y * a0.y + sa.z * a0.z + sa.w * a0.w
           + sb.x * b0.x + sb.y * b0.y + sb.z * b0.z + sb.w * b0.w;
  float z1 = sa.x * a1.x + sa.y * a1.y + sa.z * a1.z + sa.w * a1.w
           + sb.x * b1.x + sb.y * b1.y + sb.z * b1.z + sb.w * b1.w;
#pragma unroll
  for (int off = 32; off > 0; off >>= 1) {
    z0 += __shfl_down(z0, off);
    z1 += __shfl_down(z1, off);
  }
  if (lane == 0) { zs[row * 2] = z0; zs[row * 2 + 1] = z1; }
}

// fallback f32 step update (no image writes)
__global__ __launch_bounds__(256) void step_upd32(
    const float* __restrict__ gl, const float* __restrict__ gs,
    const float* __restrict__ hl_o, const float* __restrict__ cl_o,
    const float* __restrict__ cs_o,
    float* __restrict__ hl_n, float* __restrict__ cl_n,
    float* __restrict__ hs_n, float* __restrict__ cs_n,
    const float* __restrict__ zs, const float* __restrict__ Wg,
    const float* __restrict__ bg, float* __restrict__ rout, int t)
{
  const int b = blockIdx.x, tid = threadIdx.x;
  __shared__ float red0[256], red1[256];
  __shared__ float shs[512], scs[512];
  __shared__ float rsh[2];
  float4 h4 = *(const float4*)(hl_o + (long long)b * 1024 + tid * 4);
  float4 c4 = *(const float4*)(cl_o + (long long)b * 1024 + tid * 4);
  float4 w0h = *(const float4*)(Wg + 512 + tid * 4);
  float4 w0c = *(const float4*)(Wg + 1536 + tid * 4);
  float4 w1h = *(const float4*)(Wg + 2560 + 512 + tid * 4);
  float4 w1c = *(const float4*)(Wg + 2560 + 1536 + tid * 4);
  red0[tid] = h4.x * w0h.x + h4.y * w0h.y + h4.z * w0h.z + h4.w * w0h.w
            + c4.x * w0c.x + c4.y * w0c.y + c4.z * w0c.z + c4.w * w0c.w;
  red1[tid] = h4.x * w1h.x + h4.y * w1h.y + h4.z * w1h.z + h4.w * w1h.w
            + c4.x * w1c.x + c4.y * w1c.y + c4.z * w1c.z + c4.w * w1c.w;
  {
    const float* gb = gs + (long long)b * 2048;
#pragma unroll
    for (int e = 0; e < 2; ++e) {
      const int n = tid * 2 + e;
      float gi = gb[n], gf = gb[512 + n], gg = gb[1024 + n], go = gb[1536 + n];
      float c2 = sigf(gf) * cs_o[b * 512 + n] + sigf(gi) * tanhf(gg);
      float h2 = sigf(go) * tanhf(c2);
      shs[n] = h2; scs[n] = c2;
      hs_n[b * 512 + n] = h2; cs_n[b * 512 + n] = c2;
    }
  }
  __syncthreads();
  for (int s = 128; s > 0; s >>= 1) {
    if (tid < s) { red0[tid] += red0[tid + s]; red1[tid] += red1[tid + s]; }
    __syncthreads();
  }
  if (tid == 0) {
    float z0 = red0[0] + zs[(b * 64 + t) * 2 + 0] + bg[0];
    float z1 = red1[0] + zs[(b * 64 + t) * 2 + 1] + bg[1];
    int hard = (z1 > z0) ? 1 : 0;
    rsh[0] = hard ? 0.0f : 1.0f; rsh[1] = hard ? 1.0f : 0.0f;
    rout[b * 2 + 0] = rsh[0]; rout[b * 2 + 1] = rsh[1];
  }
  __syncthreads();
  const float r0 = rsh[0], r1 = rsh[1];
  {
    const float* glb = gl + (long long)b * 4096;
    const int n = tid * 4;
    float4 gi4 = *(const float4*)(glb + n);
    float4 gf4 = *(const float4*)(glb + 1024 + n);
    float4 gg4 = *(const float4*)(glb + 2048 + n);
    float4 go4 = *(const float4*)(glb + 3072 + n);
    float4 co4 = *(const float4*)(cl_o + (long long)b * 1024 + n);
    float4 ho4 = *(const float4*)(hl_o + (long long)b * 1024 + n);
    float gi[4] = {gi4.x, gi4.y, gi4.z, gi4.w};
    float gf[4] = {gf4.x, gf4.y, gf4.z, gf4.w};
    float gg[4] = {gg4.x, gg4.y, gg4.z, gg4.w};
    float go[4] = {go4.x, go4.y, go4.z, go4.w};
    float co[4] = {co4.x, co4.y, co4.z, co4.w};
    float ho[4] = {ho4.x, ho4.y, ho4.z, ho4.w};
    float hv[4], cv[4];
#pragma unroll
    for (int e = 0; e < 4; ++e) {
      float cln = sigf(gf[e]) * co[e] + sigf(gi[e]) * tanhf(gg[e]);
      float hln = sigf(go[e]) * tanhf(cln);
      float ph = (n + e < 512) ? shs[n + e] : ho[e];
      float pc = (n + e < 512) ? scs[n + e] : co[e];
      hv[e] = r0 * hln + r1 * ph;
      cv[e] = r0 * cln + r1 * pc;
    }
    float4 hw = {hv[0], hv[1], hv[2], hv[3]};
    float4 cw = {cv[0], cv[1], cv[2], cv[3]};
    *(float4*)(hl_n + (long long)b * 1024 + n) = hw;
    *(float4*)(cl_n + (long long)b * 1024 + n) = cw;
  }
}

// ===========================================================================
extern "C" void kernel_launch(void* const* d_in, const int* in_sizes, int n_in,
                              void* d_out, int out_size, void* d_ws, size_t ws_size,
                              hipStream_t stream)
{
  const float* x     = (const float*)d_in[0];
  const float* xs    = (const float*)d_in[1];
  const float* W_p   = (const float*)d_in[2];
  const float* b_p   = (const float*)d_in[3];
  const float* g_p   = (const float*)d_in[4];
  const float* be_p  = (const float*)d_in[5];
  const float* W_s   = (const float*)d_in[6];
  const float* b_s   = (const float*)d_in[7];
  const float* g_s   = (const float*)d_in[8];
  const float* be_s  = (const float*)d_in[9];
  const float* Wih_l = (const float*)d_in[10];
  const float* Whh_l = (const float*)d_in[11];
  const float* bih_l = (const float*)d_in[12];
  const float* bhh_l = (const float*)d_in[13];
  const float* Wih_s = (const float*)d_in[14];
  const float* Whh_s = (const float*)d_in[15];
  const float* bih_s = (const float*)d_in[16];
  const float* bhh_s = (const float*)d_in[17];
  const float* W_g   = (const float*)d_in[18];
  const float* b_g   = (const float*)d_in[19];
  const float* W_c   = (const float*)d_in[20];
  const float* b_c   = (const float*)d_in[21];
  float* out = (float*)d_out;
  float* r_out = out + 61184;            // [64][256][2]

  const int BT = 16384;
  const size_t FIXEDB = 100794368ULL;
  const size_t CHUNKB = 12320768ULL;
  int Tp = 0;
  for (int T = 64; T >= 1; T >>= 1)
    if (FIXEDB + CHUNKB * (size_t)T + 65536 <= ws_size) { Tp = T; break; }

  if (Tp > 0) {
    char* base = (char*)d_ws;
    size_t off = 0;
    auto alloc = [&](size_t n) { void* p = base + off; off += (n + 255) & ~255ULL; return p; };
    f16* WpI[2]  = {(f16*)alloc(8388608),  (f16*)alloc(8388608)};
    f16* WsI[2]  = {(f16*)alloc(1310720),  (f16*)alloc(1310720)};
    f16* WilI[2] = {(f16*)alloc(20971520), (f16*)alloc(20971520)};
    f16* WisI[2] = {(f16*)alloc(2097152),  (f16*)alloc(2097152)};
    f16* WhlI[2] = {(f16*)alloc(8388608),  (f16*)alloc(8388608)};
    f16* WhsI[2] = {(f16*)alloc(2097152),  (f16*)alloc(2097152)};
    f16* hlI[2] = {(f16*)alloc(524288), (f16*)alloc(524288)};
    f16* hsI[2] = {(f16*)alloc(262144), (f16*)alloc(262144)};
    float* zs  = (float*)alloc(131072);
    float* hl[2] = {(float*)alloc(1048576), (float*)alloc(1048576)};
    float* cl[2] = {(float*)alloc(1048576), (float*)alloc(1048576)};
    float* hsb[2] = {(float*)alloc(524288), (float*)alloc(524288)};
    float* csb[2] = {(float*)alloc(524288), (float*)alloc(524288)};
    float* gates_l = (float*)alloc(4194304);
    float* gates_s = (float*)alloc(2097152);
    f16* xI[2]  = {(f16*)alloc(1048576ULL * Tp), (f16*)alloc(1048576ULL * Tp)};
    f16* xsI[2] = {(f16*)alloc(655360ULL * Tp),  (f16*)alloc(655360ULL * Tp)};
    f16* feI[2] = {(f16*)alloc(1048576ULL * Tp), (f16*)alloc(1048576ULL * Tp)};
    f16* sfI[2] = {(f16*)alloc(262144ULL * Tp),  (f16*)alloc(262144ULL * Tp)};
    float* GxlC = (float*)alloc(4194304ULL * Tp);
    float* GxsC = (float*)alloc(2097152ULL * Tp);

    // one-time weight packs
    pack_img<<<2048, 256, 0, stream>>>(W_p,   2048, 64, 0, 0, WpI[0],  WpI[1],  524288);
    pack_img<<<320,  256, 0, stream>>>(W_s,   1280, 40, 0, 0, WsI[0],  WsI[1],  81920);
    pack_img<<<5120, 256, 0, stream>>>(Wih_l, 2560, 80, 0, 0, WilI[0], WilI[1], 1310720);
    pack_img<<<512,  256, 0, stream>>>(Wih_s, 512,  16, 0, 0, WisI[0], WisI[1], 131072);
    pack_img<<<2048, 256, 0, stream>>>(Whh_l, 1024, 32, 0, 0, WhlI[0], WhlI[1], 524288);
    pack_img<<<512,  256, 0, stream>>>(Whh_s, 512,  16, 0, 0, WhsI[0], WhsI[1], 131072);

    hipMemsetAsync(hl[0], 0, 1048576, stream);
    hipMemsetAsync(cl[0], 0, 1048576, stream);
    hipMemsetAsync(hsb[0], 0, 524288, stream);
    hipMemsetAsync(csb[0], 0, 524288, stream);
    hipMemsetAsync(hlI[0], 0, 524288, stream);
    hipMemsetAsync(hlI[1], 0, 524288, stream);
    hipMemsetAsync(hsI[0], 0, 262144, stream);
    hipMemsetAsync(hsI[1], 0, 262144, stream);

    const int rows = 256 * Tp;             // chunk rows (time-major)
    for (int t0 = 0; t0 < 64; t0 += Tp) {
      pack_img<<<rows * 2048 / 8 / 256, 256, 0, stream>>>(
          x, 2048, 64, t0, 1, xI[0], xI[1], rows * 256);
      pack_img<<<rows * 1280 / 8 / 256, 256, 0, stream>>>(
          xs, 1280, 40, t0, 1, xsI[0], xsI[1], rows * 160);
      // sfeats chunk -> sf image (256^2 tiles)
      gmm256<0><<<dim3(2, rows / 256), 512, 0, stream>>>(
          xsI[0], xsI[1], 40, nullptr, nullptr, 0,
          WsI[0], WsI[1], 40,
          nullptr, 0, sfI[0], sfI[1], 16, b_s, g_s, be_s);
      zs_img_k<<<rows / 4, 256, 0, stream>>>(sfI[0], sfI[1], W_g, zs, t0);
      // feats chunk -> fe image
      gmm256<0><<<dim3(8, rows / 256), 512, 0, stream>>>(
          xI[0], xI[1], 64, nullptr, nullptr, 0,
          WpI[0], WpI[1], 64,
          nullptr, 0, feI[0], feI[1], 64, b_p, g_p, be_p);
      // Gx_l = [fe|sf] @ Wih_l^T + bih_l + bhh_l
      gmm256<1><<<dim3(16, rows / 256), 512, 0, stream>>>(
          feI[0], feI[1], 64, sfI[0], sfI[1], 16,
          WilI[0], WilI[1], 80,
          GxlC, 4096, nullptr, nullptr, 0, bih_l, bhh_l, nullptr);
      // Gx_s = sf @ Wih_s^T + bih_s + bhh_s
      gmm256<1><<<dim3(8, rows / 256), 512, 0, stream>>>(
          sfI[0], sfI[1], 16, nullptr, nullptr, 0,
          WisI[0], WisI[1], 16,
          GxsC, 2048, nullptr, nullptr, 0, bih_s, bhh_s, nullptr);

      for (int tt = 0; tt < Tp; ++tt) {
        const int t = t0 + tt;
        const int o = t & 1, nw = o ^ 1;
        stepg_k<<<dim3(2, 48), 256, 0, stream>>>(
            hlI[0], hlI[1], hsI[0], hsI[1],
            WhlI[0], WhlI[1], WhsI[0], WhsI[1],
            GxlC + (long long)tt * 256 * 4096, GxsC + (long long)tt * 256 * 2048,
            gates_l, gates_s);
        step_upd<<<256, 256, 0, stream>>>(
            gates_l, gates_s, hl[o], cl[o], csb[o],
            hl[nw], cl[nw], hsb[nw], csb[nw],
            hlI[0], hlI[1], hsI[0], hsI[1],
            zs, W_g, b_g, r_out + (long long)t * 512, t);
      }
    }
    logits_k<<<256, 256, 0, stream>>>(hl[0], W_c, b_c, out);
    return;
  }

  // ---------------- all-f32 fallback (tiny workspace) ----------------
  float* ws = (float*)d_ws;
  size_t offf = 0;
  auto allocf = [&](size_t n) { float* p = ws + offf; offf += n; return p; };
  float* feats   = allocf((size_t)BT * 2048);
  float* sfeats  = allocf((size_t)BT * 512);
  float* zs      = allocf((size_t)BT * 2);
  float* gates_l = allocf((size_t)256 * 4096);
  float* gates_s = allocf((size_t)256 * 2048);
  float* hl[2] = { allocf(256 * 1024), allocf(256 * 1024) };
  float* cl[2] = { allocf(256 * 1024), allocf(256 * 1024) };
  float* hsb[2] = { allocf(256 * 512),  allocf(256 * 512) };
  float* csb[2] = { allocf(256 * 512),  allocf(256 * 512) };

  hipMemsetAsync(hl[0], 0, 256 * 1024 * sizeof(float), stream);
  hipMemsetAsync(cl[0], 0, 256 * 1024 * sizeof(float), stream);
  hipMemsetAsync(hsb[0], 0, 256 * 512 * sizeof(float), stream);
  hipMemsetAsync(csb[0], 0, 256 * 512 * sizeof(float), stream);

  gemm_nt<128, 64, 8, 4, 0><<<dim3(BT / 128, 2048 / 64), 256, 0, stream>>>(
      BT, 2048, x, 2048, W_p, 2048, 2048,
      nullptr, 0, nullptr, 0, 0, nullptr, 0, nullptr, 0, 0,
      feats, 2048, b_p, g_p, be_p);
  gemm_nt<128, 64, 8, 4, 0><<<dim3(BT / 128, 512 / 64), 256, 0, stream>>>(
      BT, 512, xs, 1280, W_s, 1280, 1280,
      nullptr, 0, nullptr, 0, 0, nullptr, 0, nullptr, 0, 0,
      sfeats, 512, b_s, g_s, be_s);
  zs32_k<<<BT / 4, 256, 0, stream>>>(sfeats, W_g, zs);

  for (int t = 0; t < 64; ++t) {
    const int o = t & 1, nw = o ^ 1;
    gemm_nt<64, 64, 4, 4, 1><<<dim3(4, 2048 / 64), 256, 0, stream>>>(
        256, 2048, sfeats + (long long)t * 512, 64LL * 512, Wih_s, 512, 512,
        hsb[o], 512, Whh_s, 512, 512, nullptr, 0, nullptr, 0, 0,
        gates_s, 2048, bih_s, bhh_s, nullptr);
    gemm_nt<64, 64, 4, 4, 1><<<dim3(4, 4096 / 64), 256, 0, stream>>>(
        256, 4096, feats + (long long)t * 2048, 64LL * 2048, Wih_l, 2560, 2048,
        sfeats + (long long)t * 512, 64LL * 512, Wih_l + 2048, 2560, 512,
        hl[o], 1024, Whh_l, 1024, 1024,
        gates_l, 4096, bih_l, bhh_l, nullptr);
    step_upd32<<<256, 256, 0, stream>>>(
        gates_l, gates_s, hl[o], cl[o], csb[o],
        hl[nw], cl[nw], hsb[nw], csb[nw],
        zs, W_g, b_g, r_out + (long long)t * 512, t);
  }
  logits_k<<<256, 256, 0, stream>>>(hl[0], W_c, b_c, out);
}